// Round 14
// baseline (1116.911 us; speedup 1.0000x reference)
//
#include <hip/hip_runtime.h>

#define BS 256
#define HS 512
#define IN_DIM 64
#define OUT_DIM 4
#define PARTS 64         // k1 blocks per batch element (8 rows each)

typedef float nfloat4 __attribute__((ext_vector_type(4)));  // for nt stores

// ---------------------------------------------------------------------------
// Kernel 1: for each row (b,i):
//   hactiv[b,i] = tanh( Wi[i,:]@x[b] + bi[i] + hidden[b,:]@w[i,:]
//                       + sum_j alpha[i,j]*hebb[b,i,j]*hidden[b,j] )
// Wave handles 2 rows; the Wi-dot rides the same 64-lane butterfly (IN_DIM=64).
// Per-block 6 head partials -> acc[b][part][6]; last block of b (atomic count)
// finalizes activout/valueout/daout. No spinning — k3's launch is the barrier.
// ---------------------------------------------------------------------------
__global__ __launch_bounds__(256, 8) void k1_kernel(
    const float* __restrict__ inputs,
    const float* __restrict__ hidden,
    const float* __restrict__ hebb,
    const float* __restrict__ Wi,  const float* __restrict__ bi,
    const float* __restrict__ w,   const float* __restrict__ alpha,
    const float* __restrict__ Wo,  const float* __restrict__ bo,
    const float* __restrict__ Wv,  const float* __restrict__ bv,
    const float* __restrict__ Wda, const float* __restrict__ bda,
    float* __restrict__ activout, float* __restrict__ valueout,
    float* __restrict__ daout,    float* __restrict__ hactiv,
    float* __restrict__ acc,      // [BS][PARTS][6]
    int* __restrict__ count)      // [BS], zeroed each call
{
    const int tid  = threadIdx.x;
    const int lane = tid & 63;
    const int wave = tid >> 6;
    const int blk  = blockIdx.x;
    const int b    = blk >> 6;
    const int part = blk & 63;
    const int iA   = (blk & 63) * 8 + wave * 2;   // row within b
    const int iB   = iA + 1;

    __shared__ float red[4][6];

    const size_t brow = (size_t)b * HS;
    const float4* __restrict__ h4 = (const float4*)(hidden + brow);
    const float4 hh0 = h4[lane];
    const float4 hh1 = h4[lane + 64];
    const float x_lane = inputs[b * IN_DIM + lane];

    const float4* __restrict__ hbA4 = (const float4*)(hebb + (brow + iA) * HS);
    const float4* __restrict__ hbB4 = (const float4*)(hebb + (brow + iB) * HS);
    const float4* __restrict__ wA4  = (const float4*)(w     + (size_t)iA * HS);
    const float4* __restrict__ wB4  = (const float4*)(w     + (size_t)iB * HS);
    const float4* __restrict__ aA4  = (const float4*)(alpha + (size_t)iA * HS);
    const float4* __restrict__ aB4  = (const float4*)(alpha + (size_t)iB * HS);

    const float4 hbA0 = hbA4[lane];
    const float4 hbA1 = hbA4[lane + 64];
    const float4 hbB0 = hbB4[lane];
    const float4 hbB1 = hbB4[lane + 64];
    const float4 wwA0 = wA4[lane];
    const float4 wwA1 = wA4[lane + 64];
    const float4 wwB0 = wB4[lane];
    const float4 wwB1 = wB4[lane + 64];
    const float4 aaA0 = aA4[lane];
    const float4 aaA1 = aA4[lane + 64];
    const float4 aaB0 = aB4[lane];
    const float4 aaB1 = aB4[lane + 64];
    const float wiA = Wi[(size_t)iA * IN_DIM + lane];
    const float wiB = Wi[(size_t)iB * IN_DIM + lane];

    float sA = wiA * x_lane;
    sA += hh0.x * (wwA0.x + aaA0.x * hbA0.x);
    sA += hh0.y * (wwA0.y + aaA0.y * hbA0.y);
    sA += hh0.z * (wwA0.z + aaA0.z * hbA0.z);
    sA += hh0.w * (wwA0.w + aaA0.w * hbA0.w);
    sA += hh1.x * (wwA1.x + aaA1.x * hbA1.x);
    sA += hh1.y * (wwA1.y + aaA1.y * hbA1.y);
    sA += hh1.z * (wwA1.z + aaA1.z * hbA1.z);
    sA += hh1.w * (wwA1.w + aaA1.w * hbA1.w);

    float sB = wiB * x_lane;
    sB += hh0.x * (wwB0.x + aaB0.x * hbB0.x);
    sB += hh0.y * (wwB0.y + aaB0.y * hbB0.y);
    sB += hh0.z * (wwB0.z + aaB0.z * hbB0.z);
    sB += hh0.w * (wwB0.w + aaB0.w * hbB0.w);
    sB += hh1.x * (wwB1.x + aaB1.x * hbB1.x);
    sB += hh1.y * (wwB1.y + aaB1.y * hbB1.y);
    sB += hh1.z * (wwB1.z + aaB1.z * hbB1.z);
    sB += hh1.w * (wwB1.w + aaB1.w * hbB1.w);

#pragma unroll
    for (int off = 32; off > 0; off >>= 1) {
        sA += __shfl_xor(sA, off, 64);    // totals land in ALL lanes
        sB += __shfl_xor(sB, off, 64);
    }

    const float hA = tanhf(sA + bi[iA]);  // uniform broadcast loads
    const float hB = tanhf(sB + bi[iB]);
    if (lane == 0) {
        hactiv[brow + iA] = hA;
        hactiv[brow + iB] = hB;
    }

    // 6 head partials (uniform across lanes)
    float p0 = hA * Wo[0 * HS + iA] + hB * Wo[0 * HS + iB];
    float p1 = hA * Wo[1 * HS + iA] + hB * Wo[1 * HS + iB];
    float p2 = hA * Wo[2 * HS + iA] + hB * Wo[2 * HS + iB];
    float p3 = hA * Wo[3 * HS + iA] + hB * Wo[3 * HS + iB];
    float p4 = hA * Wv[iA] + hB * Wv[iB];
    float p5 = hA * Wda[iA] + hB * Wda[iB];

    if (lane == 0) {
        red[wave][0] = p0; red[wave][1] = p1; red[wave][2] = p2;
        red[wave][3] = p3; red[wave][4] = p4; red[wave][5] = p5;
    }
    __syncthreads();
    if (tid < 6) {
        acc[((b << 6) + part) * 6 + tid] =
            red[0][tid] + red[1][tid] + red[2][tid] + red[3][tid];
    }
    __syncthreads();

    // last-block finalize (split-K idiom; nobody waits)
    __shared__ int s_last;
    if (tid == 0) {
        __threadfence();   // make hactiv + acc visible at agent scope
        const int prev = __hip_atomic_fetch_add(&count[b], 1, __ATOMIC_ACQ_REL,
                                                __HIP_MEMORY_SCOPE_AGENT);
        s_last = (prev == PARTS - 1);
    }
    __syncthreads();
    if (s_last) {
        if (tid == 0) __threadfence();    // acquire side before reading acc
        __syncthreads();
        if (tid < 6) {
            float s = 0.f;
            for (int q = 0; q < PARTS; ++q)
                s += acc[((b << 6) + q) * 6 + tid];
            if (tid < 4) {
                activout[b * OUT_DIM + tid] = s + bo[tid];
            } else if (tid == 4) {
                valueout[b] = s + bv[0];
            } else {
                daout[b] = tanhf(s + bda[0]);
            }
        }
    }
}

// ---------------------------------------------------------------------------
// Kernel 3: hebb_new[b,i,j] = clip(hebb + daout[b]*hactiv[b,i]*hidden[b,j]).
// R8's proven streaming body (reverse order + nt stores, 6.1 TB/s); scale is
// computed inline from daout*hactiv (both L2-resident, ~0 cost).
// ---------------------------------------------------------------------------
__global__ __launch_bounds__(256) void hebb_kernel(
    const float* __restrict__ hebb,
    const float* __restrict__ hidden,
    const float* __restrict__ daout,
    const float* __restrict__ hactiv,
    float* __restrict__ hebb_new)
{
    const long long total4 = (long long)BS * HS * HS / 4;    // 16,777,216
    const long long stride = (long long)gridDim.x * blockDim.x; // 1,048,576
    const long long tid    = (long long)blockIdx.x * blockDim.x + threadIdx.x;

#pragma unroll
    for (int k = 0; k < 16; k += 2) {
        const long long vA = total4 - 1 - tid - (long long)k * stride;
        const long long vB = vA - stride;

        const long long eA = vA * 4;
        const int bA = (int)(eA >> 18);
        const int iA = (int)(eA >> 9) & (HS - 1);
        const int jA = (int)eA & (HS - 1);
        const long long eB = vB * 4;
        const int bB = (int)(eB >> 18);
        const int iB = (int)(eB >> 9) & (HS - 1);
        const int jB = (int)eB & (HS - 1);

        const float4 hbA = ((const float4*)hebb)[vA];
        const float4 hbB = ((const float4*)hebb)[vB];
        const float  sAs = daout[bA] * hactiv[bA * HS + iA];
        const float4 hiA = *(const float4*)(hidden + bA * HS + jA);
        const float  sBs = daout[bB] * hactiv[bB * HS + iB];
        const float4 hiB = *(const float4*)(hidden + bB * HS + jB);

        nfloat4 oA, oB;
        oA.x = fminf(fmaxf(hbA.x + sAs * hiA.x, -1.f), 1.f);
        oA.y = fminf(fmaxf(hbA.y + sAs * hiA.y, -1.f), 1.f);
        oA.z = fminf(fmaxf(hbA.z + sAs * hiA.z, -1.f), 1.f);
        oA.w = fminf(fmaxf(hbA.w + sAs * hiA.w, -1.f), 1.f);
        oB.x = fminf(fmaxf(hbB.x + sBs * hiB.x, -1.f), 1.f);
        oB.y = fminf(fmaxf(hbB.y + sBs * hiB.y, -1.f), 1.f);
        oB.z = fminf(fmaxf(hbB.z + sBs * hiB.z, -1.f), 1.f);
        oB.w = fminf(fmaxf(hbB.w + sBs * hiB.w, -1.f), 1.f);
        __builtin_nontemporal_store(oA, (nfloat4*)hebb_new + vA);
        __builtin_nontemporal_store(oB, (nfloat4*)hebb_new + vB);
    }
}

extern "C" void kernel_launch(void* const* d_in, const int* in_sizes, int n_in,
                              void* d_out, int out_size, void* d_ws, size_t ws_size,
                              hipStream_t stream) {
    const float* inputs = (const float*)d_in[0];
    const float* hidden = (const float*)d_in[1];
    const float* hebb   = (const float*)d_in[2];
    const float* Wi     = (const float*)d_in[3];
    const float* bi     = (const float*)d_in[4];
    const float* w      = (const float*)d_in[5];
    const float* alpha  = (const float*)d_in[6];
    const float* Wo     = (const float*)d_in[7];
    const float* bo     = (const float*)d_in[8];
    const float* Wv     = (const float*)d_in[9];
    const float* bv     = (const float*)d_in[10];
    const float* Wda    = (const float*)d_in[11];
    const float* bda    = (const float*)d_in[12];

    float* out = (float*)d_out;
    float* activout = out;                       // [256,4]   = 1024
    float* valueout = out + 1024;                // [256,1]   = 256
    float* daout    = out + 1280;                // [256,1]   = 256
    float* hactiv   = out + 1536;                // [256,512] = 131072
    float* hebb_new = out + 1536 + BS * HS;      // [256,512,512]

    float* acc  = (float*)d_ws;                              // 384 KB
    int* count  = (int*)((char*)d_ws + (size_t)BS * PARTS * 6 * 4);

    // zero block counters each call (graph-safe, deterministic)
    hipMemsetAsync(count, 0, BS * sizeof(int), stream);

    // Kernel 1: 131072 rows, 8 rows/block -> 16384 blocks (incl. act finalize)
    k1_kernel<<<BS * PARTS, 256, 0, stream>>>(inputs, hidden, hebb, Wi, bi, w,
                                              alpha, Wo, bo, Wv, bv, Wda, bda,
                                              activout, valueout, daout, hactiv,
                                              acc, count);

    // Kernel 3: reverse streaming update, 4096 blocks
    hebb_kernel<<<4096, 256, 0, stream>>>(hebb, hidden, daout, hactiv, hebb_new);
}

// Round 15
// 139.849 us; speedup vs baseline: 7.9865x; 7.9865x over previous
//
#include <hip/hip_runtime.h>

#define BS 256
#define HS 512
#define IN_DIM 64
#define OUT_DIM 4

typedef float nfloat4 __attribute__((ext_vector_type(4)));  // native vec for nt builtins

// ---------------------------------------------------------------------------
// Kernel 1: rec[b,i] = sum_j hidden[b,j] * (w[i,j] + alpha[i,j]*hebb[b,i,j])
// Each wave handles TWO consecutive rows (same b): 12 independent float4
// loads in flight, two interleaved shfl-reduce chains. Flat grid, forward
// streaming order. ~272 MB fetch -> HBM-bound (~40-50 us).
// ---------------------------------------------------------------------------
__global__ __launch_bounds__(256) void rec_kernel(
    const float* __restrict__ hidden,
    const float* __restrict__ hebb,
    const float* __restrict__ w,
    const float* __restrict__ alpha,
    float* __restrict__ rec)
{
    const int wid  = blockIdx.x * 4 + (threadIdx.x >> 6);   // wave id
    const int lane = threadIdx.x & 63;
    const int row0 = wid * 2;                // two consecutive rows, same b
    const int b  = row0 >> 9;
    const int i0 = row0 & (HS - 1);

    const float4* __restrict__ hebb40 = (const float4*)(hebb + (size_t)row0 * HS);
    const float4* __restrict__ hebb41 = hebb40 + HS / 4;
    const float4* __restrict__ w40    = (const float4*)(w     + (size_t)i0 * HS);
    const float4* __restrict__ w41    = w40 + HS / 4;
    const float4* __restrict__ a40    = (const float4*)(alpha + (size_t)i0 * HS);
    const float4* __restrict__ a41    = a40 + HS / 4;
    const float4* __restrict__ h4     = (const float4*)(hidden + (size_t)b * HS);

    const float4 hh0 = h4[lane];
    const float4 hh1 = h4[lane + 64];

    // issue all 12 loads before consuming
    const float4 hbA0 = hebb40[lane];
    const float4 hbA1 = hebb40[lane + 64];
    const float4 hbB0 = hebb41[lane];
    const float4 hbB1 = hebb41[lane + 64];
    const float4 wwA0 = w40[lane];
    const float4 wwA1 = w40[lane + 64];
    const float4 wwB0 = w41[lane];
    const float4 wwB1 = w41[lane + 64];
    const float4 aaA0 = a40[lane];
    const float4 aaA1 = a40[lane + 64];
    const float4 aaB0 = a41[lane];
    const float4 aaB1 = a41[lane + 64];

    float sA = 0.f, sB = 0.f;
    sA += hh0.x * (wwA0.x + aaA0.x * hbA0.x);
    sA += hh0.y * (wwA0.y + aaA0.y * hbA0.y);
    sA += hh0.z * (wwA0.z + aaA0.z * hbA0.z);
    sA += hh0.w * (wwA0.w + aaA0.w * hbA0.w);
    sA += hh1.x * (wwA1.x + aaA1.x * hbA1.x);
    sA += hh1.y * (wwA1.y + aaA1.y * hbA1.y);
    sA += hh1.z * (wwA1.z + aaA1.z * hbA1.z);
    sA += hh1.w * (wwA1.w + aaA1.w * hbA1.w);

    sB += hh0.x * (wwB0.x + aaB0.x * hbB0.x);
    sB += hh0.y * (wwB0.y + aaB0.y * hbB0.y);
    sB += hh0.z * (wwB0.z + aaB0.z * hbB0.z);
    sB += hh0.w * (wwB0.w + aaB0.w * hbB0.w);
    sB += hh1.x * (wwB1.x + aaB1.x * hbB1.x);
    sB += hh1.y * (wwB1.y + aaB1.y * hbB1.y);
    sB += hh1.z * (wwB1.z + aaB1.z * hbB1.z);
    sB += hh1.w * (wwB1.w + aaB1.w * hbB1.w);

    // two independent reduce chains, interleaved
#pragma unroll
    for (int off = 32; off > 0; off >>= 1) {
        sA += __shfl_xor(sA, off, 64);
        sB += __shfl_xor(sB, off, 64);
    }
    if (lane == 0) {
        rec[row0]     = sA;
        rec[row0 + 1] = sB;
    }
}

// ---------------------------------------------------------------------------
// Kernel 2: per batch element b (one block of 512 threads, thread i = unit i):
//   hactiv[b,i] = tanh(inputs[b,:]@Wi[i,:] + bi[i] + rec[b,i])
//   activout[b,:], valueout[b], DAout[b] via block reductions
//   scale[b,i] = DAout[b] * hactiv[b,i]
// ---------------------------------------------------------------------------
__global__ __launch_bounds__(512) void act_kernel(
    const float* __restrict__ inputs,
    const float* __restrict__ Wi, const float* __restrict__ bi,
    const float* __restrict__ rec,
    const float* __restrict__ Wo, const float* __restrict__ bo,
    const float* __restrict__ Wv, const float* __restrict__ bv,
    const float* __restrict__ Wda, const float* __restrict__ bda,
    float* __restrict__ activout, float* __restrict__ valueout,
    float* __restrict__ daout, float* __restrict__ hactiv,
    float* __restrict__ scale)
{
    const int b = blockIdx.x;
    const int i = threadIdx.x;

    __shared__ __align__(16) float sh_in[IN_DIM];
    __shared__ float red[8][8];
    __shared__ float da_sh;

    if (i < IN_DIM) sh_in[i] = inputs[b * IN_DIM + i];
    __syncthreads();

    float dot = 0.f;
    const float4* __restrict__ wi4 = (const float4*)(Wi + (size_t)i * IN_DIM);
    const float4* __restrict__ in4 = (const float4*)sh_in;
#pragma unroll
    for (int t = 0; t < IN_DIM / 4; ++t) {
        const float4 a = wi4[t];
        const float4 x = in4[t];
        dot += a.x * x.x + a.y * x.y + a.z * x.z + a.w * x.w;
    }

    const float h = tanhf(dot + bi[i] + rec[(size_t)b * HS + i]);
    hactiv[(size_t)b * HS + i] = h;

    float p[6];
    p[0] = h * Wo[0 * HS + i];
    p[1] = h * Wo[1 * HS + i];
    p[2] = h * Wo[2 * HS + i];
    p[3] = h * Wo[3 * HS + i];
    p[4] = h * Wv[i];
    p[5] = h * Wda[i];

    const int lane = i & 63, wave = i >> 6;
#pragma unroll
    for (int k = 0; k < 6; ++k) {
        float s = p[k];
#pragma unroll
        for (int off = 32; off > 0; off >>= 1)
            s += __shfl_xor(s, off, 64);
        if (lane == 0) red[wave][k] = s;
    }
    __syncthreads();

    if (i < 6) {
        float s = 0.f;
#pragma unroll
        for (int wv = 0; wv < 8; ++wv) s += red[wv][i];
        if (i < 4) {
            activout[b * OUT_DIM + i] = s + bo[i];
        } else if (i == 4) {
            valueout[b] = s + bv[0];
        } else {
            const float da = tanhf(s + bda[0]);
            daout[b] = da;
            da_sh = da;
        }
    }
    __syncthreads();

    scale[(size_t)b * HS + i] = da_sh * h;
}

// ---------------------------------------------------------------------------
// Kernel 3: hebb_new[b,i,j] = clip(hebb[b,i,j] + scale[b,i]*hidden[b,j], -1, 1)
// Reverse-order streaming + nt stores (keeps the 268 MB write stream out of
// L3), 2x unrolled with both loads issued first.
// 4096 blocks x 256 threads -> exactly 16 float4s per thread, no tail.
// ---------------------------------------------------------------------------
__global__ __launch_bounds__(256) void hebb_kernel(
    const float* __restrict__ hebb,
    const float* __restrict__ hidden,
    const float* __restrict__ scale,
    float* __restrict__ hebb_new)
{
    const long long total4 = (long long)BS * HS * HS / 4;    // 16,777,216
    const long long stride = (long long)gridDim.x * blockDim.x; // 1,048,576
    const long long tid    = (long long)blockIdx.x * blockDim.x + threadIdx.x;

#pragma unroll
    for (int k = 0; k < 16; k += 2) {
        const long long vA = total4 - 1 - tid - (long long)k * stride;
        const long long vB = vA - stride;

        const long long eA = vA * 4;
        const int bA = (int)(eA >> 18);
        const int iA = (int)(eA >> 9) & (HS - 1);
        const int jA = (int)eA & (HS - 1);
        const long long eB = vB * 4;
        const int bB = (int)(eB >> 18);
        const int iB = (int)(eB >> 9) & (HS - 1);
        const int jB = (int)eB & (HS - 1);

        // issue both hebb loads before any compute/store
        const float4 hbA = ((const float4*)hebb)[vA];
        const float4 hbB = ((const float4*)hebb)[vB];
        const float  sAs = scale[bA * HS + iA];
        const float4 hiA = *(const float4*)(hidden + bA * HS + jA);
        const float  sBs = scale[bB * HS + iB];
        const float4 hiB = *(const float4*)(hidden + bB * HS + jB);

        nfloat4 oA, oB;
        oA.x = fminf(fmaxf(hbA.x + sAs * hiA.x, -1.f), 1.f);
        oA.y = fminf(fmaxf(hbA.y + sAs * hiA.y, -1.f), 1.f);
        oA.z = fminf(fmaxf(hbA.z + sAs * hiA.z, -1.f), 1.f);
        oA.w = fminf(fmaxf(hbA.w + sAs * hiA.w, -1.f), 1.f);
        oB.x = fminf(fmaxf(hbB.x + sBs * hiB.x, -1.f), 1.f);
        oB.y = fminf(fmaxf(hbB.y + sBs * hiB.y, -1.f), 1.f);
        oB.z = fminf(fmaxf(hbB.z + sBs * hiB.z, -1.f), 1.f);
        oB.w = fminf(fmaxf(hbB.w + sBs * hiB.w, -1.f), 1.f);
        __builtin_nontemporal_store(oA, (nfloat4*)hebb_new + vA);
        __builtin_nontemporal_store(oB, (nfloat4*)hebb_new + vB);
    }
}

extern "C" void kernel_launch(void* const* d_in, const int* in_sizes, int n_in,
                              void* d_out, int out_size, void* d_ws, size_t ws_size,
                              hipStream_t stream) {
    const float* inputs = (const float*)d_in[0];
    const float* hidden = (const float*)d_in[1];
    const float* hebb   = (const float*)d_in[2];
    const float* Wi     = (const float*)d_in[3];
    const float* bi     = (const float*)d_in[4];
    const float* w      = (const float*)d_in[5];
    const float* alpha  = (const float*)d_in[6];
    const float* Wo     = (const float*)d_in[7];
    const float* bo     = (const float*)d_in[8];
    const float* Wv     = (const float*)d_in[9];
    const float* bv     = (const float*)d_in[10];
    const float* Wda    = (const float*)d_in[11];
    const float* bda    = (const float*)d_in[12];

    float* out = (float*)d_out;
    float* activout = out;                       // [256,4]   = 1024
    float* valueout = out + 1024;                // [256,1]   = 256
    float* daout    = out + 1280;                // [256,1]   = 256
    float* hactiv   = out + 1536;                // [256,512] = 131072
    float* hebb_new = out + 1536 + BS * HS;      // [256,512,512]

    float* rec   = (float*)d_ws;
    float* scale = rec;   // same buffer: rec consumed before scale written

    // Kernel 1: 131072 rows, 2 rows/wave, 4 waves/block -> 16384 blocks
    rec_kernel<<<(BS * HS) / 8, 256, 0, stream>>>(hidden, hebb, w, alpha, rec);

    // Kernel 2: one block per batch element
    act_kernel<<<BS, HS, 0, stream>>>(inputs, Wi, bi, rec, Wo, bo, Wv, bv,
                                      Wda, bda, activout, valueout, daout,
                                      hactiv, scale);

    // Kernel 3: reverse streaming update, 4096 blocks
    hebb_kernel<<<4096, 256, 0, stream>>>(hebb, hidden, scale, hebb_new);
}